// Round 3
// baseline (3652.245 us; speedup 1.0000x reference)
//
#include <hip/hip_runtime.h>
#include <cstdint>
#include <cstddef>

// Problem constants (fixed by setup_inputs; groupsize==256 is d_in[4] scalar)
#define M_TOK 8192        // B*S = 4*2048 tokens
#define K_IN  4096        // IN
#define N_OUT 11008       // OUT
#define GRP   256
#define NGRP  (K_IN / GRP)   // 16
#define NT_K  (K_IN / 64)    // 64 K-tiles of BK=64

typedef float f32x4   __attribute__((ext_vector_type(4)));
typedef short bf16x8  __attribute__((ext_vector_type(8)));  // 8 bf16 = 4 VGPRs

#define WAITV(N) asm volatile("s_waitcnt vmcnt(" #N ")" ::: "memory")
#define BAR()    __builtin_amdgcn_s_barrier()

// fp32 -> bf16 round-to-nearest-even (no NaN inputs here)
__device__ inline unsigned short f2bf(float f) {
    uint32_t u = __float_as_uint(f);
    uint32_t r = (u + 0x7fffu + ((u >> 16) & 1u)) >> 16;
    return (unsigned short)r;
}

// ---------------------------------------------------------------------------
// Kernel 1: per-token dynamic int8 fake-quant -> bf16, bit-exact to reference
// ---------------------------------------------------------------------------
__global__ __launch_bounds__(256)
void quant_kernel(const float* __restrict__ x, unsigned short* __restrict__ qx)
{
    const int t   = blockIdx.x;
    const int tid = threadIdx.x;
    const float* xr = x + (size_t)t * K_IN;

    float4 v[4];
    float mn = 0.0f, mx = 0.0f;   // init 0 implements min(.,0)/max(.,0)
    #pragma unroll
    for (int j = 0; j < 4; ++j) {
        v[j] = ((const float4*)xr)[j * 256 + tid];
        mn = fminf(mn, fminf(fminf(v[j].x, v[j].y), fminf(v[j].z, v[j].w)));
        mx = fmaxf(mx, fmaxf(fmaxf(v[j].x, v[j].y), fmaxf(v[j].z, v[j].w)));
    }
    #pragma unroll
    for (int off = 32; off > 0; off >>= 1) {
        mn = fminf(mn, __shfl_xor(mn, off));
        mx = fmaxf(mx, __shfl_xor(mx, off));
    }
    __shared__ float smn[4], smx[4];
    if ((tid & 63) == 0) { smn[tid >> 6] = mn; smx[tid >> 6] = mx; }
    __syncthreads();
    mn = fminf(fminf(smn[0], smn[1]), fminf(smn[2], smn[3]));
    mx = fmaxf(fmaxf(smx[0], smx[1]), fmaxf(smx[2], smx[3]));

    const float scale = fmaxf((mx - mn) / 255.0f, 1.1920929e-7f);  // FLT_EPSILON
    const float dmin  = mn / scale;
    const float dmax  = mx / scale;
    float zp = (((-128.0f + dmin) + (127.0f + dmax)) > 0.0f) ? (-128.0f - dmin)
                                                             : (127.0f - dmax);
    zp = rintf(fminf(fmaxf(zp, -128.0f), 127.0f));

    unsigned short* qr = qx + (size_t)t * K_IN;
    #pragma unroll
    for (int j = 0; j < 4; ++j) {
        float q0 = fminf(fmaxf(rintf(v[j].x / scale) + zp, -128.0f), 127.0f);
        float q1 = fminf(fmaxf(rintf(v[j].y / scale) + zp, -128.0f), 127.0f);
        float q2 = fminf(fmaxf(rintf(v[j].z / scale) + zp, -128.0f), 127.0f);
        float q3 = fminf(fmaxf(rintf(v[j].w / scale) + zp, -128.0f), 127.0f);
        ushort4 o;
        o.x = f2bf((q0 - zp) * scale);
        o.y = f2bf((q1 - zp) * scale);
        o.z = f2bf((q2 - zp) * scale);
        o.w = f2bf((q3 - zp) * scale);
        ((ushort4*)qr)[j * 256 + tid] = o;
    }
}

// ---------------------------------------------------------------------------
// Kernel 2: groupwise int4 dequant of weights -> bf16, [N,K] row-major (B^T).
// ---------------------------------------------------------------------------
__global__ __launch_bounds__(256)
void wprep_kernel(const int* __restrict__ w, const float* __restrict__ scales,
                  const float* __restrict__ zeros, unsigned short* __restrict__ wdq)
{
    const size_t idx  = (size_t)blockIdx.x * 256 + threadIdx.x;
    const size_t base = idx * 4;                       // element index
    const int o = (int)(base >> 12);                   // /4096
    const int k = (int)(base & 4095);
    const int g = k >> 8;                              // /GRP
    const float s = scales[o * NGRP + g];
    const float z = zeros [o * NGRP + g];
    const int4 wi = *(const int4*)(w + base);
    ushort4 out;
    out.x = f2bf(((float)wi.x - z) * s);
    out.y = f2bf(((float)wi.y - z) * s);
    out.z = f2bf(((float)wi.z - z) * s);
    out.w = f2bf(((float)wi.w - z) * s);
    *(ushort4*)(wdq + base) = out;
}

// ---------------------------------------------------------------------------
// Kernel 3: bf16 GEMM, 256x256 tile, BK=64, 8-wave (2Mx4N), read-ahead 4-phase
// schedule. C[M,N] = A[M,K] * B[N,K]^T.
//
// Quadrants: q1(ph1)=a0*b0, q2(ph2)=a0*b1, q3(ph3)=a1*b1, q4(ph4)=a1*b0
// (b0 held in regs ph1->ph4: no re-read).
// ds_read schedule (24 wave-b128/tile, one phase AHEAD of first use):
//   ph2-section: b1(4) + a1(8)   (b1 own-phase; a1 for ph3/ph4)
//   ph3-section: a0'(t+1) (8)    (for t+1.ph1/ph2)
//   ph4-section: b0'(t+1) (4)    (for t+1.ph1/ph4)
// -> LDS service overlaps MFMA clusters; no blanket lgkmcnt(0) (compiler
// emits fine-grained partial waits). ONE s_barrier per phase.
//
// Stage schedule (WAR-safe: overwritten region's reads are consumed by an
// MFMA >=1 barrier before the stage can issue, or carry >=300cy MFMA+HBM
// flight margin):
//   ph1: B0(t+1)->buf^1, A1(t+1)->buf^1 ; ph2: A0(t+2)->buf ; ph4: B1(t+2)->buf
//
// vmcnt ledger (loads, oldest->newest, at each wait; 2 loads per half-tile;
// every forced load has >=2 phases of flight):
//   ph1-end  vmcnt(8): out={A1(t),A0(t+1),B1(t+1),B0(t+1),A1(t+1)}=10
//                      -> forces A1(t) (read ph2; staged t-1.ph1, 4 phases)
//   ph2-end  vmcnt(8): out={A0(t+1),B1(t+1),B0(t+1),A1(t+1),A0(t+2)}=10
//                      -> forces A0(t+1) (read ph3; staged t-1.ph2, 4 phases)
//   ph3-end  vmcnt(4): out={B1(t+1),B0(t+1),A1(t+1),A0(t+2)}=8
//                      -> forces B1(t+1) (3 phases) + B0(t+1) (read ph4, 2 ph)
// Tail: t=NT-2: ph2 vmcnt(6) [out=8], ph3 vmcnt(2) [out=6]; t=NT-1: ph1
// vmcnt(0) [out<=6, drain once]. Never 0 in steady state.
//
// Registers: acc 128 (AGPR) + peak frag-live 96 (phase-disjoint: a0 dies at
// ph2, a0' born ph3) + misc <= 256/wave -> 2 waves/SIMD preserved. Ping-pong
// via unroll-by-2 with static names (rule #20).
// ---------------------------------------------------------------------------

__device__ __forceinline__ void stage_a_half(unsigned short* dst,
                                             const unsigned short* __restrict__ A,
                                             int bm, int k0, int half, int tid)
{
    #pragma unroll
    for (int i = 0; i < 2; ++i) {
        const int c  = i * 512 + tid;                 // 16B chunk id in 16 KiB half
        const int lr = c >> 3;                        // local row 0..127
        const int cc = c & 7;                         // LDS k-chunk
        const int gc = cc ^ (lr & 7);                 // global k-chunk (swizzle)
        const int gr = ((lr >> 6) << 7) + (half << 6) + (lr & 63); // wr*128+h*64+r
        __builtin_amdgcn_global_load_lds(
            (const __attribute__((address_space(1))) void*)(A + (size_t)(bm + gr) * K_IN + k0 + (gc << 3)),
            (__attribute__((address_space(3))) void*)(dst + (size_t)c * 8),
            16, 0, 0);
    }
}

__device__ __forceinline__ void stage_b_half(unsigned short* dst,
                                             const unsigned short* __restrict__ B,
                                             int bn, int k0, int half, int tid)
{
    #pragma unroll
    for (int i = 0; i < 2; ++i) {
        const int c  = i * 512 + tid;
        const int lr = c >> 3;
        const int cc = c & 7;
        const int gc = cc ^ (lr & 7);
        const int gr = ((lr >> 5) << 6) + (half << 5) + (lr & 31); // wc*64+h*32+r
        __builtin_amdgcn_global_load_lds(
            (const __attribute__((address_space(1))) void*)(B + (size_t)(bn + gr) * K_IN + k0 + (gc << 3)),
            (__attribute__((address_space(3))) void*)(dst + (size_t)c * 8),
            16, 0, 0);
    }
}

__device__ __forceinline__ void ld_afrag(bf16x8 (&a)[4][2], const unsigned short* Ah,
                                         int wr, int lrow, int khi)
{
    #pragma unroll
    for (int mi = 0; mi < 4; ++mi) {
        const int lr = wr * 64 + mi * 16 + lrow;
        #pragma unroll
        for (int kk = 0; kk < 2; ++kk) {
            const int sc = (kk * 4 + khi) ^ (lr & 7);
            a[mi][kk] = *(const bf16x8*)(Ah + lr * 64 + sc * 8);
        }
    }
}

__device__ __forceinline__ void ld_bfrag(bf16x8 (&b)[2][2], const unsigned short* Bh,
                                         int wc, int lrow, int khi)
{
    #pragma unroll
    for (int ni = 0; ni < 2; ++ni) {
        const int lr = wc * 32 + ni * 16 + lrow;
        #pragma unroll
        for (int kk = 0; kk < 2; ++kk) {
            const int sc = (kk * 4 + khi) ^ (lr & 7);
            b[ni][kk] = *(const bf16x8*)(Bh + lr * 64 + sc * 8);
        }
    }
}

template<int MH, int NH>
__device__ __forceinline__ void mfma_quad(f32x4 (&acc)[8][4],
                                          const bf16x8 (&a)[4][2],
                                          const bf16x8 (&b)[2][2])
{
    __builtin_amdgcn_s_setprio(1);
    #pragma unroll
    for (int kk = 0; kk < 2; ++kk)
        #pragma unroll
        for (int mi = 0; mi < 4; ++mi)
            #pragma unroll
            for (int ni = 0; ni < 2; ++ni)
                acc[MH * 4 + mi][NH * 2 + ni] =
                    __builtin_amdgcn_mfma_f32_16x16x32_bf16(
                        a[mi][kk], b[ni][kk], acc[MH * 4 + mi][NH * 2 + ni], 0, 0, 0);
    __builtin_amdgcn_s_setprio(0);
}

template<int BUF>
__device__ __forceinline__ void ktile_body(
    int t, const unsigned short* __restrict__ A, const unsigned short* __restrict__ B,
    unsigned short* Asb, unsigned short* Bsb,
    int bm, int bn, int tid, int wr, int wc, int lrow, int khi,
    f32x4 (&acc)[8][4],
    bf16x8 (&a_cur)[4][2], bf16x8 (&b_cur)[2][2],
    bf16x8 (&a_nxt)[4][2], bf16x8 (&b_nxt)[2][2])
{
    const bool p1 = t < NT_K - 1;
    const bool p2 = t < NT_K - 2;
    unsigned short* AsC = Asb + BUF * 16384;         // current buffer
    unsigned short* BsC = Bsb + BUF * 16384;
    unsigned short* AsN = Asb + (BUF ^ 1) * 16384;   // next buffer
    unsigned short* BsN = Bsb + (BUF ^ 1) * 16384;

    // ---- ph1: q1 = a0 x b0; stage B0(t+1), A1(t+1) -> buf^1
    if (p1) {
        stage_b_half(BsN,        B, bn, (t + 1) << 6, 0, tid);
        stage_a_half(AsN + 8192, A, bm, (t + 1) << 6, 1, tid);
        WAITV(8);
    } else {
        WAITV(0);
    }
    BAR();
    mfma_quad<0, 0>(acc, a_cur, b_cur);

    // ---- ph2: q2 = a0 x b1; read b1 (own-phase) + a1 (ahead); stage A0(t+2)
    bf16x8 b1[2][2], a1[4][2];
    ld_bfrag(b1, BsC + 8192, wc, lrow, khi);
    ld_afrag(a1, AsC + 8192, wr, lrow, khi);
    if (p2)      { stage_a_half(AsC, A, bm, (t + 2) << 6, 0, tid); WAITV(8); }
    else if (p1) { WAITV(6); }
    BAR();
    mfma_quad<0, 1>(acc, a_cur, b1);

    // ---- ph3: q3 = a1 x b1; read a0'(t+1) ahead
    if (p1) ld_afrag(a_nxt, AsN, wr, lrow, khi);
    if (p2)      { WAITV(4); }
    else if (p1) { WAITV(2); }
    BAR();
    mfma_quad<1, 1>(acc, a1, b1);

    // ---- ph4: q4 = a1 x b0 (b0 held since ph1); read b0'(t+1); stage B1(t+2)
    if (p1) ld_bfrag(b_nxt, BsN, wc, lrow, khi);
    if (p2) stage_b_half(BsC + 8192, B, bn, (t + 2) << 6, 1, tid);
    BAR();
    mfma_quad<1, 0>(acc, a1, b_cur);
}

__global__ __launch_bounds__(512, 2)
void gemm_kernel(const unsigned short* __restrict__ A,   // [M_TOK, K_IN] bf16
                 const unsigned short* __restrict__ B,   // [N_OUT, K_IN] bf16
                 float* __restrict__ C)                  // [M_TOK, N_OUT] f32
{
    __shared__ unsigned short As[2][2][8192];  // [buf][mhalf] 64 KiB
    __shared__ unsigned short Bs[2][2][8192];  // [buf][nhalf] 64 KiB
    unsigned short* Asb = &As[0][0][0];
    unsigned short* Bsb = &Bs[0][0][0];

    const int tid  = threadIdx.x;
    const int lane = tid & 63;
    const int wave = tid >> 6;
    const int wr   = wave >> 2;          // 0..1  (M half of tile, 128 rows)
    const int wc   = wave & 3;           // 0..3  (N quarter of tile, 64 cols)
    const int lrow = lane & 15;
    const int khi  = lane >> 4;          // 0..3

    // T1: XCD-aware swizzle; grid = 43*32 = 1376 = 8*172 (bijective)
    const int bid = blockIdx.x;
    const int swz = (bid & 7) * 172 + (bid >> 3);
    const int bm  = (swz / 43) * 256;
    const int bn  = (swz % 43) * 256;

    // Prologue (6 stages = 12 loads, oldest->newest):
    //   A0(0), B0(0), A1(0), B1(0), A0(1), B1(1)
    // (B0(1)/A1(1) come from t0.ph1; A0(2)/B1(2) from t0.ph2/ph4.)
    stage_a_half(Asb,                A, bm, 0,  0, tid);   // A0(0)
    stage_b_half(Bsb,                B, bn, 0,  0, tid);   // B0(0)
    stage_a_half(Asb + 8192,         A, bm, 0,  1, tid);   // A1(0)
    stage_b_half(Bsb + 8192,         B, bn, 0,  1, tid);   // B1(0)
    stage_a_half(Asb + 16384,        A, bm, 64, 0, tid);   // A0(1)
    stage_b_half(Bsb + 16384 + 8192, B, bn, 64, 1, tid);   // B1(1)
    WAITV(8);                        // forces A0(0), B0(0) (oldest 4 loads)
    BAR();

    f32x4 acc[8][4] = {};
    bf16x8 aA[4][2], bA[2][2], aB[4][2], bB[2][2];
    // Loop invariant: (a_cur, b_cur) hold tile t's q1 operands at body entry.
    ld_afrag(aA, Asb, wr, lrow, khi);
    ld_bfrag(bA, Bsb, wc, lrow, khi);

    for (int t = 0; t < NT_K; t += 2) {
        ktile_body<0>(t,     A, B, Asb, Bsb, bm, bn, tid, wr, wc, lrow, khi,
                      acc, aA, bA, aB, bB);
        ktile_body<1>(t + 1, A, B, Asb, Bsb, bm, bn, tid, wr, wc, lrow, khi,
                      acc, aB, bB, aA, bA);
    }

    // Epilogue: C/D layout (verified m89/m91): col = lane&15, row = (lane>>4)*4 + reg
    const int crow = khi * 4;
    #pragma unroll
    for (int mi = 0; mi < 8; ++mi) {
        #pragma unroll
        for (int ni = 0; ni < 4; ++ni) {
            const f32x4 v = acc[mi][ni];
            const int m0 = bm + wr * 128 + mi * 16 + crow;
            const int n0 = bn + wc * 64 + ni * 16 + lrow;
            #pragma unroll
            for (int r = 0; r < 4; ++r)
                C[(size_t)(m0 + r) * N_OUT + n0] = v[r];
        }
    }
}

// ---------------------------------------------------------------------------
extern "C" void kernel_launch(void* const* d_in, const int* in_sizes, int n_in,
                              void* d_out, int out_size, void* d_ws, size_t ws_size,
                              hipStream_t stream)
{
    const float* x      = (const float*)d_in[0];  // [4,2048,4096] f32
    const int*   w      = (const int*)  d_in[1];  // [11008,4096] int32 in [-8,7]
    const float* scales = (const float*)d_in[2];  // [11008,16] f32
    const float* zeros  = (const float*)d_in[3];  // [11008,16] f32
    float* out = (float*)d_out;                   // [8192,11008] f32

    unsigned short* qx  = (unsigned short*)d_ws;
    unsigned short* wdq = qx + (size_t)M_TOK * K_IN;

    quant_kernel<<<M_TOK, 256, 0, stream>>>(x, qx);
    wprep_kernel<<<(int)(((size_t)N_OUT * K_IN / 4) / 256), 256, 0, stream>>>(w, scales, zeros, wdq);
    gemm_kernel<<<1376, 512, 0, stream>>>(qx, wdq, out);
}

// Round 4
// 1210.793 us; speedup vs baseline: 3.0164x; 3.0164x over previous
//
#include <hip/hip_runtime.h>
#include <cstdint>
#include <cstddef>

// Problem constants (fixed by setup_inputs; groupsize==256 is d_in[4] scalar)
#define M_TOK 8192        // B*S = 4*2048 tokens
#define K_IN  4096        // IN
#define N_OUT 11008       // OUT
#define GRP   256
#define NGRP  (K_IN / GRP)   // 16
#define NT_K  (K_IN / 64)    // 64 K-tiles of BK=64
#define WPREP_BLOCKS ((N_OUT * K_IN / 4) / 256)   // 44032

typedef float f32x4   __attribute__((ext_vector_type(4)));
typedef short bf16x8  __attribute__((ext_vector_type(8)));  // 8 bf16 = 4 VGPRs

#define WAITV(N) asm volatile("s_waitcnt vmcnt(" #N ")" ::: "memory")
#define BAR()    __builtin_amdgcn_s_barrier()

// fp32 -> bf16 round-to-nearest-even (no NaN inputs here)
__device__ inline unsigned short f2bf(float f) {
    uint32_t u = __float_as_uint(f);
    uint32_t r = (u + 0x7fffu + ((u >> 16) & 1u)) >> 16;
    return (unsigned short)r;
}

// ---------------------------------------------------------------------------
// Kernel 1 (fused prep): blocks [0, M_TOK) do per-token int8 fake-quant of
// activations -> bf16; blocks [M_TOK, M_TOK+WPREP_BLOCKS) do groupwise int4
// dequant of weights -> bf16 [N,K] row-major. Fusing the two independent
// memory-bound passes into one launch lets them overlap on the grid instead
// of serializing on the stream.
// ---------------------------------------------------------------------------
__global__ __launch_bounds__(256)
void prep_kernel(const float* __restrict__ x, unsigned short* __restrict__ qx,
                 const int* __restrict__ w, const float* __restrict__ scales,
                 const float* __restrict__ zeros, unsigned short* __restrict__ wdq)
{
    const int tid = threadIdx.x;
    if (blockIdx.x < M_TOK) {
        // ---- activation quant (bit-exact to round-0/1 version) ----
        const int t = blockIdx.x;
        const float* xr = x + (size_t)t * K_IN;

        float4 v[4];
        float mn = 0.0f, mx = 0.0f;   // init 0 implements min(.,0)/max(.,0)
        #pragma unroll
        for (int j = 0; j < 4; ++j) {
            v[j] = ((const float4*)xr)[j * 256 + tid];
            mn = fminf(mn, fminf(fminf(v[j].x, v[j].y), fminf(v[j].z, v[j].w)));
            mx = fmaxf(mx, fmaxf(fmaxf(v[j].x, v[j].y), fmaxf(v[j].z, v[j].w)));
        }
        #pragma unroll
        for (int off = 32; off > 0; off >>= 1) {
            mn = fminf(mn, __shfl_xor(mn, off));
            mx = fmaxf(mx, __shfl_xor(mx, off));
        }
        __shared__ float smn[4], smx[4];
        if ((tid & 63) == 0) { smn[tid >> 6] = mn; smx[tid >> 6] = mx; }
        __syncthreads();
        mn = fminf(fminf(smn[0], smn[1]), fminf(smn[2], smn[3]));
        mx = fmaxf(fmaxf(smx[0], smx[1]), fmaxf(smx[2], smx[3]));

        const float scale = fmaxf((mx - mn) / 255.0f, 1.1920929e-7f);
        const float dmin  = mn / scale;
        const float dmax  = mx / scale;
        float zp = (((-128.0f + dmin) + (127.0f + dmax)) > 0.0f) ? (-128.0f - dmin)
                                                                 : (127.0f - dmax);
        zp = rintf(fminf(fmaxf(zp, -128.0f), 127.0f));

        unsigned short* qr = qx + (size_t)t * K_IN;
        #pragma unroll
        for (int j = 0; j < 4; ++j) {
            float q0 = fminf(fmaxf(rintf(v[j].x / scale) + zp, -128.0f), 127.0f);
            float q1 = fminf(fmaxf(rintf(v[j].y / scale) + zp, -128.0f), 127.0f);
            float q2 = fminf(fmaxf(rintf(v[j].z / scale) + zp, -128.0f), 127.0f);
            float q3 = fminf(fmaxf(rintf(v[j].w / scale) + zp, -128.0f), 127.0f);
            ushort4 o;
            o.x = f2bf((q0 - zp) * scale);
            o.y = f2bf((q1 - zp) * scale);
            o.z = f2bf((q2 - zp) * scale);
            o.w = f2bf((q3 - zp) * scale);
            ((ushort4*)qr)[j * 256 + tid] = o;
        }
    } else {
        // ---- weight dequant ----
        const size_t idx  = (size_t)(blockIdx.x - M_TOK) * 256 + tid;
        const size_t base = idx * 4;                       // element index
        const int o = (int)(base >> 12);                   // /4096
        const int k = (int)(base & 4095);
        const int g = k >> 8;                              // /GRP
        const float s = scales[o * NGRP + g];
        const float z = zeros [o * NGRP + g];
        const int4 wi = *(const int4*)(w + base);
        ushort4 out;
        out.x = f2bf(((float)wi.x - z) * s);
        out.y = f2bf(((float)wi.y - z) * s);
        out.z = f2bf(((float)wi.z - z) * s);
        out.w = f2bf(((float)wi.w - z) * s);
        *(ushort4*)(wdq + base) = out;
    }
}

// ---------------------------------------------------------------------------
// Kernel 2: bf16 GEMM, 256x256 tile, BK=64, 8 waves (2Mx4N). Round-1 proven
// structure (2 barriers/phase, same-phase frag reads, verified stage/vmcnt
// ledger) with the two measured overheads removed:
//   1. NO blanket lgkmcnt(0) / sched_barrier(0): the compiler emits partial
//      per-register lgkm waits, so LDS service of later frags overlaps the
//      earlier MFMAs of the phase. Correctness: every frag read's staging was
//      forced by the vmcnt (memory-clobber asm) at the PREVIOUS tile's ph4 +
//      barrier, and reads cannot hoist above that asm.
//   2. All addressing hoisted out of the K-loop: 4 per-lane LDS frag offsets,
//      4 induction global source pointers (+64 elems/tile), 2 LDS dest bases.
//   3. b0 held in regs ph1->ph4 (24 reads/tile instead of 28).
//
// Quadrants: ph1 q1=a0*b0, ph2 q2=a0*b1, ph3 q3=a1*b1, ph4 q4=a1*b0.
// Stages: ph1 B0(t+1)->buf^1; ph2 A0(t+2)->buf; ph3 B1(t+2)->buf;
//         ph4 A1(t+2)->buf.
// WAR (exact, no margins): each restaged region's frags are fully consumed by
// the MFMA quad that precedes the stage's barrier (a0 by q1 < ph2 stage; b1 by
// q2 < ph3 stage; a1 by q3 < ph4 stage; next-buf B0 free since t-1.ph1) --
// consumption implies the ds_read completed; BAR-OUT orders all waves.
// RAW: at ph4, outstanding = {A0,B1,A1,B0}(t+1) + {A0,B1,A1}(t+2) = 14 loads;
// vmcnt(6) forces the oldest 8 = ALL of tile t+1. Tail: t=NT-2 -> vmcnt(0).
// Registers: acc 128 + frag peak 64 (a0+b0+b1 or a1+b1+b0) + ~24 misc ~= 220.
// ---------------------------------------------------------------------------

__device__ __forceinline__ void stage2(const unsigned short* g, unsigned short* l)
{
    // load i covers LDS chunk c = i*512 + tid; global row(i=1) = row(i=0)+128.
    __builtin_amdgcn_global_load_lds(
        (const __attribute__((address_space(1))) void*)g,
        (__attribute__((address_space(3))) void*)l, 16, 0, 0);
    __builtin_amdgcn_global_load_lds(
        (const __attribute__((address_space(1))) void*)(g + (size_t)128 * K_IN),
        (__attribute__((address_space(3))) void*)(l + 4096), 16, 0, 0);
}

__device__ __forceinline__ void ld_a(bf16x8 (&a)[4][2], const unsigned short* base,
                                     int off0, int off1)
{
    #pragma unroll
    for (int mi = 0; mi < 4; ++mi) {
        a[mi][0] = *(const bf16x8*)(base + off0 + mi * 1024);
        a[mi][1] = *(const bf16x8*)(base + off1 + mi * 1024);
    }
}

__device__ __forceinline__ void ld_b(bf16x8 (&b)[2][2], const unsigned short* base,
                                     int off0, int off1)
{
    #pragma unroll
    for (int ni = 0; ni < 2; ++ni) {
        b[ni][0] = *(const bf16x8*)(base + off0 + ni * 1024);
        b[ni][1] = *(const bf16x8*)(base + off1 + ni * 1024);
    }
}

template<int MH, int NH>
__device__ __forceinline__ void mfma_quad(f32x4 (&acc)[8][4],
                                          const bf16x8 (&a)[4][2],
                                          const bf16x8 (&b)[2][2])
{
    __builtin_amdgcn_s_setprio(1);
    #pragma unroll
    for (int kk = 0; kk < 2; ++kk)
        #pragma unroll
        for (int mi = 0; mi < 4; ++mi)
            #pragma unroll
            for (int ni = 0; ni < 2; ++ni)
                acc[MH * 4 + mi][NH * 2 + ni] =
                    __builtin_amdgcn_mfma_f32_16x16x32_bf16(
                        a[mi][kk], b[ni][kk], acc[MH * 4 + mi][NH * 2 + ni], 0, 0, 0);
    __builtin_amdgcn_s_setprio(0);
}

__global__ __launch_bounds__(512, 2)
void gemm_kernel(const unsigned short* __restrict__ A,   // [M_TOK, K_IN] bf16
                 const unsigned short* __restrict__ B,   // [N_OUT, K_IN] bf16
                 float* __restrict__ C)                  // [M_TOK, N_OUT] f32
{
    __shared__ unsigned short As[2][2][8192];  // [buf][mhalf] 64 KiB
    __shared__ unsigned short Bs[2][2][8192];  // [buf][nhalf] 64 KiB
    unsigned short* AsF = &As[0][0][0];
    unsigned short* BsF = &Bs[0][0][0];

    const int tid  = threadIdx.x;
    const int lane = tid & 63;
    const int wave = tid >> 6;
    const int wr   = wave >> 2;          // 0..1  (M half, 128 rows)
    const int wc   = wave & 3;           // 0..3  (N quarter, 64 cols)
    const int lrow = lane & 15;
    const int khi  = lane >> 4;          // 0..3

    // T1: XCD-aware swizzle; grid = 43*32 = 1376 = 8*172 (bijective)
    const int bid = blockIdx.x;
    const int swz = (bid & 7) * 172 + (bid >> 3);
    const int bm  = (swz / 43) * 256;
    const int bn  = (swz % 43) * 256;

    // --- hoisted per-lane LDS frag offsets (shorts); sc = (kk*4+khi)^(lr&7),
    // lr&7 == lrow&7 for every frag row this lane touches.
    const int sw    = lrow & 7;
    const int offA0 = (wr * 64 + lrow) * 64 + ((khi       ^ sw) << 3);
    const int offA1 = (wr * 64 + lrow) * 64 + (((khi + 4) ^ sw) << 3);
    const int offB0 = (wc * 32 + lrow) * 64 + ((khi       ^ sw) << 3);
    const int offB1 = (wc * 32 + lrow) * 64 + (((khi + 4) ^ sw) << 3);

    // --- hoisted stage addressing. Load i=0 covers LDS chunks tid (lr=tid>>3
    // in 0..63); source row: A half h -> h*64+lr ; B half h -> (lr>>5)*64 +
    // h*32 + (lr&31). Swizzled source k-chunk = (tid&7)^(lr&7).
    const int slr = tid >> 3;
    const int sgc = ((tid & 7) ^ (slr & 7)) << 3;
    const unsigned short* sA0 = A + (size_t)(bm +      slr) * K_IN + sgc;
    const unsigned short* sA1 = A + (size_t)(bm + 64 + slr) * K_IN + sgc;
    const int brow = ((slr >> 5) << 6) + (slr & 31);
    const unsigned short* sB0 = B + (size_t)(bn + brow     ) * K_IN + sgc;
    const unsigned short* sB1 = B + (size_t)(bn + brow + 32) * K_IN + sgc;
    unsigned short* dA = AsF + tid * 8;    // dest base, half0/buf0 (shorts)
    unsigned short* dB = BsF + tid * 8;

    // Prologue (oldest->newest): A0(0) B0(0) B1(0) A1(0) A0(1) B1(1) A1(1)
    // = 14 loads; vmcnt(6) forces the oldest 8 = tile 0 complete.
    stage2(sA0, dA);                 sA0 += 64;
    stage2(sB0, dB);                 sB0 += 64;
    stage2(sB1, dB + 8192);          sB1 += 64;
    stage2(sA1, dA + 8192);          sA1 += 64;
    stage2(sA0, dA + 16384);         sA0 += 64;
    stage2(sB1, dB + 16384 + 8192);  sB1 += 64;
    stage2(sA1, dA + 16384 + 8192);  sA1 += 64;
    WAITV(6);
    BAR();

    f32x4 acc[8][4] = {};

    for (int t = 0; t < NT_K; ++t) {
        const int bo  = (t & 1) << 14;       // current buf offset (shorts)
        const int bon = bo ^ 16384;          // next buf
        const bool p1 = t < NT_K - 1;
        const bool p2 = t < NT_K - 2;
        bf16x8 a0[4][2], a1[4][2], b0[2][2], b1[2][2];

        // ---- ph1: q1 = a0 x b0; stage B0(t+1) -> next buf
        ld_a(a0, AsF + bo, offA0, offA1);
        ld_b(b0, BsF + bo, offB0, offB1);
        if (p1) stage2(sB0, dB + bon);
        sB0 += 64;
        BAR();
        mfma_quad<0, 0>(acc, a0, b0);
        BAR();

        // ---- ph2: q2 = a0 x b1; stage A0(t+2) -> cur buf (a0 consumed by q1)
        ld_b(b1, BsF + bo + 8192, offB0, offB1);
        if (p2) stage2(sA0, dA + bo);
        sA0 += 64;
        BAR();
        mfma_quad<0, 1>(acc, a0, b1);
        BAR();

        // ---- ph3: q3 = a1 x b1; stage B1(t+2) -> cur buf (b1 consumed by q2)
        ld_a(a1, AsF + bo + 8192, offA0, offA1);
        if (p2) stage2(sB1, dB + bo + 8192);
        sB1 += 64;
        BAR();
        mfma_quad<1, 1>(acc, a1, b1);
        BAR();

        // ---- ph4: q4 = a1 x b0 (b0 held since ph1); stage A1(t+2) -> cur buf
        if (p2) stage2(sA1, dA + bo + 8192);
        sA1 += 64;
        if (p2)      { WAITV(6); }           // forces ALL of tile t+1 (8 of 14)
        else if (p1) { WAITV(0); }           // t = NT-2: drain once
        BAR();
        mfma_quad<1, 0>(acc, a1, b0);
        BAR();
    }

    // Epilogue: C/D layout (verified m89/m91): col = lane&15, row = (lane>>4)*4 + reg
    const int crow = khi * 4;
    #pragma unroll
    for (int mi = 0; mi < 8; ++mi) {
        #pragma unroll
        for (int ni = 0; ni < 4; ++ni) {
            const f32x4 v = acc[mi][ni];
            const int m0 = bm + wr * 128 + mi * 16 + crow;
            const int n0 = bn + wc * 64 + ni * 16 + lrow;
            #pragma unroll
            for (int r = 0; r < 4; ++r)
                C[(size_t)(m0 + r) * N_OUT + n0] = v[r];
        }
    }
}

// ---------------------------------------------------------------------------
extern "C" void kernel_launch(void* const* d_in, const int* in_sizes, int n_in,
                              void* d_out, int out_size, void* d_ws, size_t ws_size,
                              hipStream_t stream)
{
    const float* x      = (const float*)d_in[0];  // [4,2048,4096] f32
    const int*   w      = (const int*)  d_in[1];  // [11008,4096] int32 in [-8,7]
    const float* scales = (const float*)d_in[2];  // [11008,16] f32
    const float* zeros  = (const float*)d_in[3];  // [11008,16] f32
    float* out = (float*)d_out;                   // [8192,11008] f32

    unsigned short* qx  = (unsigned short*)d_ws;
    unsigned short* wdq = qx + (size_t)M_TOK * K_IN;

    prep_kernel<<<M_TOK + WPREP_BLOCKS, 256, 0, stream>>>(x, qx, w, scales, zeros, wdq);
    gemm_kernel<<<1376, 512, 0, stream>>>(qx, wdq, out);
}